// Round 6
// baseline (569.213 us; speedup 1.0000x reference)
//
#include <hip/hip_runtime.h>
#include <hip/hip_bf16.h>

#define DEV __device__ __forceinline__

typedef short bf16x8 __attribute__((ext_vector_type(8)));
typedef float f32x4 __attribute__((ext_vector_type(4)));
typedef unsigned short u16x4 __attribute__((ext_vector_type(4)));

static constexpr int Bsz = 4, Tt = 2048, Cch = 2048, Dd = 128, Ee = 16;
static constexpr int Nn = Bsz * Tt;
static constexpr int CAP = 2048;  // per-expert token capacity (mean ~1024, sigma ~30)
static constexpr size_t PHALF = (size_t)Ee * CAP * 384;  // elems per split-K partial

DEV unsigned short f2bf(float v) {
    __hip_bfloat16 h = __float2bfloat16(v);
    return __builtin_bit_cast(unsigned short, h);
}
DEV float bf2f(unsigned short u) {
    unsigned int x = ((unsigned int)u) << 16;
    return __builtin_bit_cast(float, x);
}

// ---------------- sim_matrix column norms ----------------
__global__ __launch_bounds__(256) void colnorm_kernel(const float* __restrict__ sim,
                                                      float* __restrict__ sninv) {
    int e = threadIdx.x & 15, j = threadIdx.x >> 4;
    float ss = 0.f;
    for (int r = j; r < Cch; r += 16) {
        float v = sim[r * Ee + e];
        ss += v * v;
    }
    __shared__ float red[16][17];
    red[j][e] = ss;
    __syncthreads();
    if (threadIdx.x < 16) {
        float s = 0.f;
        for (int t = 0; t < 16; t++) s += red[t][threadIdx.x];
        sninv[threadIdx.x] = 1.f / fmaxf(sqrtf(s), 1e-12f);
    }
}

// ---------------- sim transpose: simT[e][c] = sim[c][e] ----------------
__global__ __launch_bounds__(256) void simt_kernel(const float* __restrict__ sim,
                                                   float* __restrict__ simT) {
    int i = blockIdx.x * 256 + threadIdx.x;  // 16*2048
    int e = i >> 11, c = i & 2047;
    simT[i] = sim[c * 16 + e];
}

// ---------------- gating: 1 wave per token, NO atomics; writes rw + onmask ----------------
__global__ __launch_bounds__(256) void gating2_kernel(
    const float* __restrict__ x, const float* __restrict__ simT,
    const float* __restrict__ gates, const float* __restrict__ sninv,
    const int* __restrict__ minex,
    float* __restrict__ rw, unsigned short* __restrict__ xb,
    int* __restrict__ onmaskv) {
    const int wave = threadIdx.x >> 6, lane = threadIdx.x & 63;
    const int n = blockIdx.x * 4 + wave;
    const f32x4* xr = (const f32x4*)(x + (size_t)n * Cch);
    const f32x4* st = (const f32x4*)simT;
    u16x4* xbr = (u16x4*)(xb + (size_t)n * Cch);
    float ss = 0.f;
    float d[16];
#pragma unroll
    for (int e = 0; e < 16; e++) d[e] = 0.f;
#pragma unroll
    for (int it = 0; it < 8; it++) {
        int i = it * 64 + lane;
        f32x4 xv = xr[i];
        ss += xv[0] * xv[0] + xv[1] * xv[1] + xv[2] * xv[2] + xv[3] * xv[3];
        u16x4 xc = {f2bf(xv[0]), f2bf(xv[1]), f2bf(xv[2]), f2bf(xv[3])};
        xbr[i] = xc;
#pragma unroll
        for (int e = 0; e < 16; e++) {
            f32x4 sv = st[e * 512 + i];
            d[e] += xv[0] * sv[0] + xv[1] * sv[1] + xv[2] * sv[2] + xv[3] * sv[3];
        }
    }
#pragma unroll
    for (int off = 32; off; off >>= 1) {
        ss += __shfl_down(ss, off);
#pragma unroll
        for (int e = 0; e < 16; e++) d[e] += __shfl_down(d[e], off);
    }
    if (lane == 0) {
        float inv = 1.f / fmaxf(sqrtf(ss), 1e-12f);
        float logit[16];
        int onmask = 0;
#pragma unroll
        for (int e = 0; e < 16; e++) {
            float sg = 1.f / (1.f + __expf(-gates[e]));
            float l = d[e] * inv * sninv[e] - sg;
            logit[e] = l;
            if (l > 0.f) onmask |= (1 << e);
        }
        if (onmask == 0) {
            int k = *minex;
            int ch = 0;
            for (int kk = 0; kk < k; kk++) {
                float bv = -1e30f;
                int be = 0;
#pragma unroll
                for (int e = 0; e < 16; e++)
                    if (!((ch >> e) & 1) && logit[e] > bv) { bv = logit[e]; be = e; }
                ch |= (1 << be);
            }
            onmask = ch;
        }
        float mx = -1e30f;
#pragma unroll
        for (int e = 0; e < 16; e++)
            if ((onmask >> e) & 1) mx = fmaxf(mx, fmaxf(logit[e], 0.f));
        float pe[16];
        float sum = 0.f;
#pragma unroll
        for (int e = 0; e < 16; e++) {
            pe[e] = ((onmask >> e) & 1) ? __expf(fmaxf(logit[e], 0.f) - mx) : 0.f;
            sum += pe[e];
        }
        float isum = 1.f / sum;
#pragma unroll
        for (int e = 0; e < 16; e++) rw[(size_t)n * 16 + e] = pe[e] * isum;
        onmaskv[n] = onmask;
    }
}

// ---------------- deterministic expert-list + rank-list scan ----------------
__global__ __launch_bounds__(256) void scan_kernel(
    const int* __restrict__ onmaskv,
    int* __restrict__ idx, int* __restrict__ pos, int* __restrict__ cnt,
    int* __restrict__ idxr0, int* __restrict__ idxr1, int* __restrict__ cntr) {
    const int e = blockIdx.x;
    const int tid = threadIdx.x;
    const int base = tid * 32;
    int cA = 0, c0 = 0, c1 = 0;
    for (int i = 0; i < 32; i++) {
        int m = onmaskv[base + i];
        int on = (m >> e) & 1;
        int r = __popc(m & ((1 << e) - 1));
        cA += on;
        c0 += (on && r == 0) ? 1 : 0;
        c1 += (on && r == 1) ? 1 : 0;
    }
    const int lane = tid & 63, w = tid >> 6;
    int sA = cA, s0 = c0, s1 = c1;
#pragma unroll
    for (int off = 1; off < 64; off <<= 1) {
        int tA = __shfl_up(sA, off), t0 = __shfl_up(s0, off), t1 = __shfl_up(s1, off);
        if (lane >= off) { sA += tA; s0 += t0; s1 += t1; }
    }
    __shared__ int wsA[4], ws0[4], ws1[4];
    if (lane == 63) { wsA[w] = sA; ws0[w] = s0; ws1[w] = s1; }
    __syncthreads();
    int bA = 0, b0 = 0, b1 = 0;
    for (int i = 0; i < w; i++) { bA += wsA[i]; b0 += ws0[i]; b1 += ws1[i]; }
    int slotA = bA + sA - cA, slot0 = b0 + s0 - c0, slot1 = b1 + s1 - c1;
    for (int i = 0; i < 32; i++) {
        int n = base + i;
        int m = onmaskv[n];
        int on = (m >> e) & 1;
        int r = __popc(m & ((1 << e) - 1));
        int p = -1;
        if (on) {
            if (slotA < CAP) { idx[(size_t)e * CAP + slotA] = n; p = slotA; }
            slotA++;
            if (r == 0) { if (slot0 < CAP) idxr0[(size_t)e * CAP + slot0] = n; slot0++; }
            else if (r == 1) { if (slot1 < CAP) idxr1[(size_t)e * CAP + slot1] = n; slot1++; }
        }
        pos[(size_t)n * 16 + e] = p;
    }
    if (tid == 255) { cnt[e] = slotA; cntr[e] = slot0; cntr[16 + e] = slot1; }
}

// ---------------- transposes ----------------
__global__ __launch_bounds__(256) void transpose_f32_bf16(
    const float* __restrict__ src, unsigned short* __restrict__ dst,
    int R, int Ccol, long ss, long ds) {
    __shared__ float tile[32][33];
    src += (size_t)blockIdx.z * ss;
    dst += (size_t)blockIdx.z * ds;
    int bx = blockIdx.x * 32, by = blockIdx.y * 32;
    int tx = threadIdx.x & 31, ty = threadIdx.x >> 5;
#pragma unroll
    for (int i = 0; i < 4; i++)
        tile[ty + i * 8][tx] = src[(size_t)(by + ty + i * 8) * Ccol + bx + tx];
    __syncthreads();
#pragma unroll
    for (int i = 0; i < 4; i++)
        dst[(size_t)(bx + ty + i * 8) * R + by + tx] = f2bf(tile[tx][ty + i * 8]);
}

__global__ __launch_bounds__(256) void transpose_u16(
    const unsigned short* __restrict__ src, unsigned short* __restrict__ dst,
    int R, int Ccol, long ss, long ds) {
    __shared__ unsigned short tile[32][33];
    src += (size_t)blockIdx.z * ss;
    dst += (size_t)blockIdx.z * ds;
    int bx = blockIdx.x * 32, by = blockIdx.y * 32;
    int tx = threadIdx.x & 31, ty = threadIdx.x >> 5;
#pragma unroll
    for (int i = 0; i < 4; i++)
        tile[ty + i * 8][tx] = src[(size_t)(by + ty + i * 8) * Ccol + bx + tx];
    __syncthreads();
#pragma unroll
    for (int i = 0; i < 4; i++)
        dst[(size_t)(bx + ty + i * 8) * R + by + tx] = tile[tx][ty + i * 8];
}

// ---------------- NT GEMM: Out[M,N] = A[M,K] * BT[N,K]^T (bf16 in, f32 out) ----------------
template <int CAUSAL>
__global__ __launch_bounds__(256) void gemm_nt(
    const unsigned short* __restrict__ A, long strideA, int lda,
    const unsigned short* __restrict__ BT, long strideB, int ldb,
    float* __restrict__ Out, long strideO, int ldo,
    int K, float scale) {
    __shared__ alignas(16) unsigned short As[128 * 64];
    __shared__ alignas(16) unsigned short Bs[128 * 64];
    const int bm = blockIdx.x * 128;
    const int bn = blockIdx.y * 128;
    if (CAUSAL && bn > bm + 127) return;
    A += (size_t)blockIdx.z * strideA;
    BT += (size_t)blockIdx.z * strideB;
    Out += (size_t)blockIdx.z * strideO;
    const int tid = threadIdx.x;
    const int wave = tid >> 6, lane = tid & 63;
    const int lr = lane & 15, lg = lane >> 4;
    const int wr = (wave >> 1) * 64, wc = (wave & 1) * 64;
    f32x4 acc[4][4] = {};

    for (int k0 = 0; k0 < K; k0 += 64) {
        __syncthreads();
#pragma unroll
        for (int i = 0; i < 4; i++) {
            int t = i * 256 + tid;
            int row = t >> 3;
            int kc = (t & 7) << 3;
            __builtin_amdgcn_global_load_lds(
                (const __attribute__((address_space(1))) void*)(A + (size_t)(bm + row) * lda + k0 + kc),
                (__attribute__((address_space(3))) void*)(As + (i * 4 + wave) * 512),
                16, 0, 0);
        }
#pragma unroll
        for (int i = 0; i < 4; i++) {
            int t = i * 256 + tid;
            int row = t >> 3;
            int kc = (t & 7) << 3;
            __builtin_amdgcn_global_load_lds(
                (const __attribute__((address_space(1))) void*)(BT + (size_t)(bn + row) * ldb + k0 + kc),
                (__attribute__((address_space(3))) void*)(Bs + (i * 4 + wave) * 512),
                16, 0, 0);
        }
        __syncthreads();
#pragma unroll
        for (int kk = 0; kk < 2; kk++) {
            bf16x8 a[4], b[4];
#pragma unroll
            for (int m = 0; m < 4; m++)
                a[m] = *(const bf16x8*)(As + (wr + m * 16 + lr) * 64 + kk * 32 + lg * 8);
#pragma unroll
            for (int n = 0; n < 4; n++)
                b[n] = *(const bf16x8*)(Bs + (wc + n * 16 + lr) * 64 + kk * 32 + lg * 8);
#pragma unroll
            for (int m = 0; m < 4; m++)
#pragma unroll
                for (int n = 0; n < 4; n++)
                    acc[m][n] = __builtin_amdgcn_mfma_f32_16x16x32_bf16(a[m], b[n], acc[m][n], 0, 0, 0);
        }
    }
#pragma unroll
    for (int m = 0; m < 4; m++) {
#pragma unroll
        for (int n = 0; n < 4; n++) {
#pragma unroll
            for (int r = 0; r < 4; r++) {
                int grow = bm + wr + m * 16 + lg * 4 + r;
                int gcol = bn + wc + n * 16 + lr;
                if (!CAUSAL || gcol <= grow)
                    Out[(size_t)grow * ldo + gcol] = acc[m][n][r] * scale;
            }
        }
    }
}

// ---------------- PV GEMM: split-K over causal-active chunks, atomic f32 accumulate ----------------
__global__ __launch_bounds__(256) void gemm_pv(
    const unsigned short* __restrict__ P, const unsigned short* __restrict__ vT,
    float* __restrict__ ob) {
    const int bm = blockIdx.x * 128;
    const int kb = blockIdx.y * 512;
    if (kb > bm + 127) return;
    const unsigned short* Pb = P + (size_t)blockIdx.z * Tt * 4096;
    const unsigned short* Vb = vT + (size_t)blockIdx.z * Dd * Tt;
    float* Ob = ob + (size_t)blockIdx.z * Tt * Dd;
    __shared__ alignas(16) unsigned short As[128 * 64];
    __shared__ alignas(16) unsigned short Bs[128 * 64];
    const int tid = threadIdx.x;
    const int wave = tid >> 6, lane = tid & 63;
    const int lr = lane & 15, lg = lane >> 4;
    const int wr = (wave >> 1) * 64, wc = (wave & 1) * 64;
    f32x4 acc[4][4] = {};

    for (int k0 = kb; k0 < kb + 512; k0 += 64) {
        __syncthreads();
#pragma unroll
        for (int i = 0; i < 4; i++) {
            int t = i * 256 + tid;
            int row = t >> 3;
            int kc = (t & 7) << 3;
            __builtin_amdgcn_global_load_lds(
                (const __attribute__((address_space(1))) void*)(Pb + (size_t)(bm + row) * 4096 + k0 + kc),
                (__attribute__((address_space(3))) void*)(As + (i * 4 + wave) * 512),
                16, 0, 0);
        }
#pragma unroll
        for (int i = 0; i < 4; i++) {
            int t = i * 256 + tid;
            int row = t >> 3;
            int kc = (t & 7) << 3;
            __builtin_amdgcn_global_load_lds(
                (const __attribute__((address_space(1))) void*)(Vb + (size_t)row * Tt + k0 + kc),
                (__attribute__((address_space(3))) void*)(Bs + (i * 4 + wave) * 512),
                16, 0, 0);
        }
        __syncthreads();
#pragma unroll
        for (int kk = 0; kk < 2; kk++) {
            bf16x8 a[4], b[4];
#pragma unroll
            for (int m = 0; m < 4; m++)
                a[m] = *(const bf16x8*)(As + (wr + m * 16 + lr) * 64 + kk * 32 + lg * 8);
#pragma unroll
            for (int n = 0; n < 4; n++)
                b[n] = *(const bf16x8*)(Bs + (wc + n * 16 + lr) * 64 + kk * 32 + lg * 8);
#pragma unroll
            for (int m = 0; m < 4; m++)
#pragma unroll
                for (int n = 0; n < 4; n++)
                    acc[m][n] = __builtin_amdgcn_mfma_f32_16x16x32_bf16(a[m], b[n], acc[m][n], 0, 0, 0);
        }
    }
#pragma unroll
    for (int m = 0; m < 4; m++)
#pragma unroll
        for (int n = 0; n < 4; n++)
#pragma unroll
            for (int r = 0; r < 4; r++) {
                int grow = bm + wr + m * 16 + lg * 4 + r;
                int gcol = wc + n * 16 + lr;
                atomicAdd(&Ob[(size_t)grow * Dd + gcol], acc[m][n][r]);
            }
}

// ---------------- gathered QKV projection, split-K=2 into bf16 partial halves ----------------
__global__ __launch_bounds__(256) void gemm_qkv_gather(
    const unsigned short* __restrict__ X, const unsigned short* __restrict__ W,
    const int* __restrict__ idx, const int* __restrict__ cnt,
    unsigned short* __restrict__ P) {
    const int z = blockIdx.z;  // e*2 + kchunk
    const int e = z >> 1, kc2 = z & 1;
    const int cn = min(cnt[e], CAP);
    const int bm = blockIdx.x * 128;
    if (bm >= cn) return;
    const int bn = blockIdx.y * 128;
    unsigned short* Ph = P + (size_t)kc2 * PHALF;
    __shared__ alignas(16) unsigned short As[128 * 64];
    __shared__ alignas(16) unsigned short Bs[128 * 64];
    __shared__ int toks[128];
    const int tid = threadIdx.x;
    if (tid < 128) toks[tid] = idx[(size_t)e * CAP + min(bm + tid, cn - 1)];
    const unsigned short* Wb = W + ((size_t)e * 384 + bn) * Cch;
    const int wave = tid >> 6, lane = tid & 63;
    const int lr = lane & 15, lg = lane >> 4;
    const int wr = (wave >> 1) * 64, wc = (wave & 1) * 64;
    f32x4 acc[4][4] = {};

    for (int k0 = kc2 * 1024; k0 < kc2 * 1024 + 1024; k0 += 64) {
        __syncthreads();
#pragma unroll
        for (int i = 0; i < 4; i++) {
            int t = i * 256 + tid;
            int row = t >> 3;
            int kc = (t & 7) << 3;
            __builtin_amdgcn_global_load_lds(
                (const __attribute__((address_space(1))) void*)(X + (size_t)toks[row] * Cch + k0 + kc),
                (__attribute__((address_space(3))) void*)(As + (i * 4 + wave) * 512),
                16, 0, 0);
        }
#pragma unroll
        for (int i = 0; i < 4; i++) {
            int t = i * 256 + tid;
            int row = t >> 3;
            int kc = (t & 7) << 3;
            __builtin_amdgcn_global_load_lds(
                (const __attribute__((address_space(1))) void*)(Wb + (size_t)row * Cch + k0 + kc),
                (__attribute__((address_space(3))) void*)(Bs + (i * 4 + wave) * 512),
                16, 0, 0);
        }
        __syncthreads();
#pragma unroll
        for (int kk = 0; kk < 2; kk++) {
            bf16x8 a[4], b[4];
#pragma unroll
            for (int m = 0; m < 4; m++)
                a[m] = *(const bf16x8*)(As + (wr + m * 16 + lr) * 64 + kk * 32 + lg * 8);
#pragma unroll
            for (int n = 0; n < 4; n++)
                b[n] = *(const bf16x8*)(Bs + (wc + n * 16 + lr) * 64 + kk * 32 + lg * 8);
#pragma unroll
            for (int m = 0; m < 4; m++)
#pragma unroll
                for (int n = 0; n < 4; n++)
                    acc[m][n] = __builtin_amdgcn_mfma_f32_16x16x32_bf16(a[m], b[n], acc[m][n], 0, 0, 0);
        }
    }
#pragma unroll
    for (int m = 0; m < 4; m++)
#pragma unroll
        for (int n = 0; n < 4; n++)
#pragma unroll
            for (int r = 0; r < 4; r++) {
                int slot = bm + wr + m * 16 + lg * 4 + r;
                int col = bn + wc + n * 16 + lr;
                if (slot < cn)
                    Ph[((size_t)e * CAP + slot) * 384 + col] = f2bf(acc[m][n][r]);
            }
}

// ---------------- combine q/k/v from two split-K halves ----------------
__global__ __launch_bounds__(256) void combine_qkv(
    const unsigned short* __restrict__ P, const float* __restrict__ rw,
    const int* __restrict__ pos,
    unsigned short* __restrict__ qb, unsigned short* __restrict__ kb,
    unsigned short* __restrict__ vb) {
    int i = blockIdx.x * 256 + threadIdx.x;
    int n = i >> 5;
    int d4 = (i & 31) << 2;
    float aq[4] = {}, ak[4] = {}, av[4] = {};
#pragma unroll
    for (int e = 0; e < 16; e++) {
        int p = pos[(size_t)n * 16 + e];
        if (p >= 0) {
            float w = rw[(size_t)n * 16 + e];
            const unsigned short* r0 = P + ((size_t)e * CAP + p) * 384 + d4;
            const unsigned short* r1 = r0 + PHALF;
            const u16x4 q0 = *(const u16x4*)(r0);
            const u16x4 k0 = *(const u16x4*)(r0 + 128);
            const u16x4 v0 = *(const u16x4*)(r0 + 256);
            const u16x4 q1 = *(const u16x4*)(r1);
            const u16x4 k1 = *(const u16x4*)(r1 + 128);
            const u16x4 v1 = *(const u16x4*)(r1 + 256);
#pragma unroll
            for (int j = 0; j < 4; j++) {
                aq[j] += w * (bf2f(q0[j]) + bf2f(q1[j]));
                ak[j] += w * (bf2f(k0[j]) + bf2f(k1[j]));
                av[j] += w * (bf2f(v0[j]) + bf2f(v1[j]));
            }
        }
    }
    u16x4 sq = {f2bf(aq[0]), f2bf(aq[1]), f2bf(aq[2]), f2bf(aq[3])};
    u16x4 sk = {f2bf(ak[0]), f2bf(ak[1]), f2bf(ak[2]), f2bf(ak[3])};
    u16x4 sv = {f2bf(av[0]), f2bf(av[1]), f2bf(av[2]), f2bf(av[3])};
    *(u16x4*)(qb + (size_t)n * Dd + d4) = sq;
    *(u16x4*)(kb + (size_t)n * Dd + d4) = sk;
    *(u16x4*)(vb + (size_t)n * Dd + d4) = sv;
}

// ---------------- causal row softmax, in-place f32 -> bf16 ----------------
__global__ __launch_bounds__(256) void softmax_kernel(float* __restrict__ scores) {
    int i = blockIdx.x, b = blockIdx.y;
    float* row = scores + ((size_t)b * Tt + i) * Tt;
    int nv = i + 1;
    float v[8];
    int cnt = 0;
    float mx = -1e30f;
    for (int j = threadIdx.x; j < nv; j += 256) {
        float t = row[j];
        v[cnt++] = t;
        mx = fmaxf(mx, t);
    }
    __shared__ float sred[4];
    int w = threadIdx.x >> 6;
#pragma unroll
    for (int off = 32; off; off >>= 1) mx = fmaxf(mx, __shfl_down(mx, off));
    if ((threadIdx.x & 63) == 0) sred[w] = mx;
    __syncthreads();
    float m = fmaxf(fmaxf(sred[0], sred[1]), fmaxf(sred[2], sred[3]));
    float s = 0.f;
    for (int t = 0; t < cnt; t++) {
        v[t] = __expf(v[t] - m);
        s += v[t];
    }
    __syncthreads();
#pragma unroll
    for (int off = 32; off; off >>= 1) s += __shfl_down(s, off);
    if ((threadIdx.x & 63) == 0) sred[w] = s;
    __syncthreads();
    float inv = 1.f / (sred[0] + sred[1] + sred[2] + sred[3]);
    unsigned short* prow = (unsigned short*)row;
    cnt = 0;
    for (int j = threadIdx.x; j < Tt; j += 256) {
        float pv = 0.f;
        if (j < nv) pv = v[cnt++] * inv;
        prow[j] = f2bf(pv);
    }
}

// ---------------- obb = bf16(ob) ----------------
__global__ __launch_bounds__(256) void obb_kernel(const float* __restrict__ ob,
                                                  unsigned short* __restrict__ obb) {
    int i = blockIdx.x * 256 + threadIdx.x;  // per 4 elems
    const f32x4 v = *(const f32x4*)(ob + (size_t)i * 4);
    u16x4 st = {f2bf(v[0]), f2bf(v[1]), f2bf(v[2]), f2bf(v[3])};
    *(u16x4*)(obb + (size_t)i * 4) = st;
}

// ---------------- rank-grouped output projection, B-resident + A-pipelined ----------------
// one block per (bn, e); B-tile (op[e] cols bn..bn+127, K=128) lives in LDS;
// loop over token chunks of the rank list with double-buffered A staging.
template <int ADD>
__global__ __launch_bounds__(256) void gemm_out2(
    const unsigned short* __restrict__ obb,   // [Nn][128] bf16
    const unsigned short* __restrict__ woT,   // [2048 c][E*128] bf16
    const int* __restrict__ idxr, const int* __restrict__ cntr,
    const float* __restrict__ rw,
    float* __restrict__ out) {
    const int e = blockIdx.y;
    const int cn = min(cntr[e], CAP);
    if (cn == 0) return;
    const int bn = blockIdx.x * 128;
    const int nchunk = (cn + 127) >> 7;
    __shared__ alignas(16) unsigned short Bs[128 * 128];
    __shared__ alignas(16) unsigned short As[2][128 * 128];
    __shared__ int toks[2][128];
    __shared__ float rwv[2][128];
    const int tid = threadIdx.x;
    const int wave = tid >> 6, lane = tid & 63;
    const int lr = lane & 15, lg = lane >> 4;
    const int wr = (wave >> 1) * 64, wc = (wave & 1) * 64;
    const int* idxe = idxr + (size_t)e * CAP;

    // stage B once: Bs[n][k] = woT[(bn+n)*2048 + e*128 + k]
#pragma unroll
    for (int i = 0; i < 8; i++) {
        int t = i * 256 + tid;
        int row = t >> 4;
        int kc = (t & 15) << 3;
        __builtin_amdgcn_global_load_lds(
            (const __attribute__((address_space(1))) void*)(woT + (size_t)(bn + row) * 2048 + e * 128 + kc),
            (__attribute__((address_space(3))) void*)(Bs + (i * 4 + wave) * 512),
            16, 0, 0);
    }

    auto stageA = [&](int buf, int bm) {
#pragma unroll
        for (int i = 0; i < 8; i++) {
            int t = i * 256 + tid;
            int row = t >> 4;
            int kc = (t & 15) << 3;
            int tok = idxe[min(bm + row, cn - 1)];
            __builtin_amdgcn_global_load_lds(
                (const __attribute__((address_space(1))) void*)(obb + (size_t)tok * 128 + kc),
                (__attribute__((address_space(3))) void*)(As[buf] + (i * 4 + wave) * 512),
                16, 0, 0);
        }
        if (tid < 128) {
            int tok = idxe[min(bm + tid, cn - 1)];
            toks[buf][tid] = tok;
            rwv[buf][tid] = rw[(size_t)tok * 16 + e];
        }
    };

    stageA(0, 0);
    int cur = 0;
    for (int c = 0; c < nchunk; c++) {
        __syncthreads();  // drains vmcnt: B + As[cur] + toks[cur] ready
        if (c + 1 < nchunk) stageA(cur ^ 1, (c + 1) << 7);
        f32x4 acc[4][4] = {};
#pragma unroll
        for (int kk = 0; kk < 4; kk++) {
            bf16x8 a[4], b[4];
#pragma unroll
            for (int m = 0; m < 4; m++)
                a[m] = *(const bf16x8*)(As[cur] + (wr + m * 16 + lr) * 128 + kk * 32 + lg * 8);
#pragma unroll
            for (int n = 0; n < 4; n++)
                b[n] = *(const bf16x8*)(Bs + (wc + n * 16 + lr) * 128 + kk * 32 + lg * 8);
#pragma unroll
            for (int m = 0; m < 4; m++)
#pragma unroll
                for (int n = 0; n < 4; n++)
                    acc[m][n] = __builtin_amdgcn_mfma_f32_16x16x32_bf16(a[m], b[n], acc[m][n], 0, 0, 0);
        }
        const int bm = c << 7;
#pragma unroll
        for (int m = 0; m < 4; m++)
#pragma unroll
            for (int n = 0; n < 4; n++)
#pragma unroll
                for (int r = 0; r < 4; r++) {
                    int rowt = wr + m * 16 + lg * 4 + r;
                    if (bm + rowt < cn) {
                        int tok = toks[cur][rowt];
                        float v = rwv[cur][rowt] * acc[m][n][r];
                        size_t o = (size_t)tok * 2048 + bn + wc + n * 16 + lr;
                        if (ADD) out[o] += v; else out[o] = v;
                    }
                }
        cur ^= 1;
    }
}

extern "C" void kernel_launch(void* const* d_in, const int* in_sizes, int n_in,
                              void* d_out, int out_size, void* d_ws, size_t ws_size,
                              hipStream_t stream) {
    (void)in_sizes; (void)n_in; (void)out_size; (void)ws_size;
    const float* hidden = (const float*)d_in[0];
    const float* sim = (const float*)d_in[1];
    const float* gates = (const float*)d_in[2];
    const float* qp = (const float*)d_in[3];
    const float* kp = (const float*)d_in[4];
    const float* vp = (const float*)d_in[5];
    const float* op = (const float*)d_in[6];
    const int* minex = (const int*)d_in[7];
    float* out = (float*)d_out;

    char* w = (char*)d_ws;
    size_t off = 0;
    auto alloc = [&](size_t bytes) -> char* {
        char* p = w + off;
        off = (off + bytes + 255) & ~(size_t)255;
        return p;
    };
    unsigned short* xb = (unsigned short*)alloc((size_t)Nn * Cch * 2);
    unsigned short* wqkvT = (unsigned short*)alloc((size_t)Ee * 384 * Cch * 2);
    unsigned short* woT = (unsigned short*)alloc((size_t)Cch * Ee * Dd * 2);
    float* rw = (float*)alloc((size_t)Nn * Ee * 4);
    float* sninv = (float*)alloc(256);
    float* simT = (float*)alloc((size_t)Ee * Cch * 4);
    int* cnt = (int*)alloc(256);
    int* cntr = (int*)alloc(256);
    int* onmaskv = (int*)alloc((size_t)Nn * 4);
    int* idx = (int*)alloc((size_t)Ee * CAP * 4);
    int* idxr0 = (int*)alloc((size_t)Ee * CAP * 4);
    int* idxr1 = (int*)alloc((size_t)Ee * CAP * 4);
    int* pos = (int*)alloc((size_t)Nn * 16 * 4);
    char* big = alloc((size_t)Bsz * Tt * Tt * 4);  // P halves (50MB) / scores (67MB)
    unsigned short* qb = (unsigned short*)alloc((size_t)Nn * Dd * 2);
    unsigned short* kb = (unsigned short*)alloc((size_t)Nn * Dd * 2);
    unsigned short* vb = (unsigned short*)alloc((size_t)Nn * Dd * 2);
    unsigned short* vT = (unsigned short*)alloc((size_t)Bsz * Dd * Tt * 2);
    float* ob = (float*)alloc((size_t)Nn * Dd * 4);
    unsigned short* obb = (unsigned short*)alloc((size_t)Nn * Dd * 2);
    unsigned short* Pc = (unsigned short*)big;
    float* scores = (float*)big;

    const float scale = 0.08838834764831845f;  // 1/sqrt(128)

    colnorm_kernel<<<1, 256, 0, stream>>>(sim, sninv);
    simt_kernel<<<(Ee * Cch) / 256, 256, 0, stream>>>(sim, simT);
    gating2_kernel<<<Nn / 4, 256, 0, stream>>>(hidden, simT, gates, sninv, minex, rw, xb, onmaskv);
    scan_kernel<<<Ee, 256, 0, stream>>>(onmaskv, idx, pos, cnt, idxr0, idxr1, cntr);
    hipMemsetAsync(ob, 0, (size_t)Nn * Dd * 4, stream);

    // weight transposes (f32 -> bf16) into fused [E][384][C]
    transpose_f32_bf16<<<dim3(Dd / 32, Cch / 32, Ee), 256, 0, stream>>>(
        qp, wqkvT + 0 * Dd * Cch, Cch, Dd, (long)Cch * Dd, (long)384 * Cch);
    transpose_f32_bf16<<<dim3(Dd / 32, Cch / 32, Ee), 256, 0, stream>>>(
        kp, wqkvT + 1 * Dd * Cch, Cch, Dd, (long)Cch * Dd, (long)384 * Cch);
    transpose_f32_bf16<<<dim3(Dd / 32, Cch / 32, Ee), 256, 0, stream>>>(
        vp, wqkvT + 2 * Dd * Cch, Cch, Dd, (long)Cch * Dd, (long)384 * Cch);
    transpose_f32_bf16<<<dim3((Ee * Dd) / 32, Cch / 32, 1), 256, 0, stream>>>(
        op, woT, Ee * Dd, Cch, 0L, 0L);

    // gathered per-expert QKV projection (split-K=2), then combine
    gemm_qkv_gather<<<dim3(CAP / 128, 3, Ee * 2), 256, 0, stream>>>(xb, wqkvT, idx, cnt, Pc);
    combine_qkv<<<(Nn * 32) / 256, 256, 0, stream>>>(Pc, rw, pos, qb, kb, vb);

    // V transpose per batch
    transpose_u16<<<dim3(Dd / 32, Tt / 32, Bsz), 256, 0, stream>>>(
        vb, vT, Tt, Dd, (long)Tt * Dd, (long)Dd * Tt);

    // scores = Q K^T * scale (causal)
    gemm_nt<1><<<dim3(Tt / 128, Tt / 128, Bsz), 256, 0, stream>>>(
        qb, (long)Tt * Dd, Dd, kb, (long)Tt * Dd, Dd, scores, (long)Tt * Tt, Tt, Dd, scale);
    softmax_kernel<<<dim3(Tt, Bsz), 256, 0, stream>>>(scores);
    // O = P V  — split-K over causal-active 512-chunks, atomic accumulate
    gemm_pv<<<dim3(Tt / 128, Tt / 512, Bsz), 256, 0, stream>>>(
        (const unsigned short*)scores, vT, ob);

    // output projection: rank-0 stores, rank-1 accumulates (stream-ordered, unique writers)
    obb_kernel<<<(Nn * Dd / 4) / 256, 256, 0, stream>>>(ob, obb);
    gemm_out2<0><<<dim3(Cch / 128, Ee), 256, 0, stream>>>(obb, woT, idxr0, cntr, rw, out);
    gemm_out2<1><<<dim3(Cch / 128, Ee), 256, 0, stream>>>(obb, woT, idxr1, cntr + 16, rw, out);
}

// Round 7
// 384.603 us; speedup vs baseline: 1.4800x; 1.4800x over previous
//
#include <hip/hip_runtime.h>
#include <hip/hip_bf16.h>

#define DEV __device__ __forceinline__

typedef short bf16x8 __attribute__((ext_vector_type(8)));
typedef float f32x4 __attribute__((ext_vector_type(4)));
typedef unsigned short u16x4 __attribute__((ext_vector_type(4)));

static constexpr int Bsz = 4, Tt = 2048, Cch = 2048, Dd = 128, Ee = 16;
static constexpr int Nn = Bsz * Tt;
static constexpr int CAP = 2048;  // per-expert token capacity (mean ~1024, sigma ~30)
static constexpr size_t PHALF = (size_t)Ee * CAP * 384;  // elems per split-K partial
static constexpr int MAXTILES = 320;  // >= 256 buckets + Nn/128

DEV unsigned short f2bf(float v) {
    __hip_bfloat16 h = __float2bfloat16(v);
    return __builtin_bit_cast(unsigned short, h);
}
DEV float bf2f(unsigned short u) {
    unsigned int x = ((unsigned int)u) << 16;
    return __builtin_bit_cast(float, x);
}

// ---------------- sim_matrix column norms ----------------
__global__ __launch_bounds__(256) void colnorm_kernel(const float* __restrict__ sim,
                                                      float* __restrict__ sninv) {
    int e = threadIdx.x & 15, j = threadIdx.x >> 4;
    float ss = 0.f;
    for (int r = j; r < Cch; r += 16) {
        float v = sim[r * Ee + e];
        ss += v * v;
    }
    __shared__ float red[16][17];
    red[j][e] = ss;
    __syncthreads();
    if (threadIdx.x < 16) {
        float s = 0.f;
        for (int t = 0; t < 16; t++) s += red[t][threadIdx.x];
        sninv[threadIdx.x] = 1.f / fmaxf(sqrtf(s), 1e-12f);
    }
}

// ---------------- sim transpose: simT[e][c] = sim[c][e] ----------------
__global__ __launch_bounds__(256) void simt_kernel(const float* __restrict__ sim,
                                                   float* __restrict__ simT) {
    int i = blockIdx.x * 256 + threadIdx.x;  // 16*2048
    int e = i >> 11, c = i & 2047;
    simT[i] = sim[c * 16 + e];
}

// ---------------- gating: 1 wave per token, NO atomics; writes rw + onmask ----------------
__global__ __launch_bounds__(256) void gating2_kernel(
    const float* __restrict__ x, const float* __restrict__ simT,
    const float* __restrict__ gates, const float* __restrict__ sninv,
    const int* __restrict__ minex,
    float* __restrict__ rw, unsigned short* __restrict__ xb,
    int* __restrict__ onmaskv) {
    const int wave = threadIdx.x >> 6, lane = threadIdx.x & 63;
    const int n = blockIdx.x * 4 + wave;
    const f32x4* xr = (const f32x4*)(x + (size_t)n * Cch);
    const f32x4* st = (const f32x4*)simT;
    u16x4* xbr = (u16x4*)(xb + (size_t)n * Cch);
    float ss = 0.f;
    float d[16];
#pragma unroll
    for (int e = 0; e < 16; e++) d[e] = 0.f;
#pragma unroll
    for (int it = 0; it < 8; it++) {
        int i = it * 64 + lane;
        f32x4 xv = xr[i];
        ss += xv[0] * xv[0] + xv[1] * xv[1] + xv[2] * xv[2] + xv[3] * xv[3];
        u16x4 xc = {f2bf(xv[0]), f2bf(xv[1]), f2bf(xv[2]), f2bf(xv[3])};
        xbr[i] = xc;
#pragma unroll
        for (int e = 0; e < 16; e++) {
            f32x4 sv = st[e * 512 + i];
            d[e] += xv[0] * sv[0] + xv[1] * sv[1] + xv[2] * sv[2] + xv[3] * sv[3];
        }
    }
#pragma unroll
    for (int off = 32; off; off >>= 1) {
        ss += __shfl_down(ss, off);
#pragma unroll
        for (int e = 0; e < 16; e++) d[e] += __shfl_down(d[e], off);
    }
    if (lane == 0) {
        float inv = 1.f / fmaxf(sqrtf(ss), 1e-12f);
        float logit[16];
        int onmask = 0;
#pragma unroll
        for (int e = 0; e < 16; e++) {
            float sg = 1.f / (1.f + __expf(-gates[e]));
            float l = d[e] * inv * sninv[e] - sg;
            logit[e] = l;
            if (l > 0.f) onmask |= (1 << e);
        }
        if (onmask == 0) {
            int k = *minex;
            int ch = 0;
            for (int kk = 0; kk < k; kk++) {
                float bv = -1e30f;
                int be = 0;
#pragma unroll
                for (int e = 0; e < 16; e++)
                    if (!((ch >> e) & 1) && logit[e] > bv) { bv = logit[e]; be = e; }
                ch |= (1 << be);
            }
            onmask = ch;
        }
        float mx = -1e30f;
#pragma unroll
        for (int e = 0; e < 16; e++)
            if ((onmask >> e) & 1) mx = fmaxf(mx, fmaxf(logit[e], 0.f));
        float pe[16];
        float sum = 0.f;
#pragma unroll
        for (int e = 0; e < 16; e++) {
            pe[e] = ((onmask >> e) & 1) ? __expf(fmaxf(logit[e], 0.f) - mx) : 0.f;
            sum += pe[e];
        }
        float isum = 1.f / sum;
#pragma unroll
        for (int e = 0; e < 16; e++) rw[(size_t)n * 16 + e] = pe[e] * isum;
        onmaskv[n] = onmask;
    }
}

// ---------------- deterministic expert-list scan (for QKV gather) ----------------
__global__ __launch_bounds__(256) void scan_kernel(
    const int* __restrict__ onmaskv,
    int* __restrict__ idx, int* __restrict__ pos, int* __restrict__ cnt) {
    const int e = blockIdx.x;
    const int tid = threadIdx.x;
    const int base = tid * 32;
    int om[32];
    int c = 0;
#pragma unroll
    for (int i = 0; i < 32; i++) {
        om[i] = (onmaskv[base + i] >> e) & 1;
        c += om[i];
    }
    const int lane = tid & 63, w = tid >> 6;
    int sc = c;
#pragma unroll
    for (int off = 1; off < 64; off <<= 1) {
        int t = __shfl_up(sc, off);
        if (lane >= off) sc += t;
    }
    __shared__ int wsum[4];
    if (lane == 63) wsum[w] = sc;
    __syncthreads();
    int wbase = 0;
    for (int i = 0; i < w; i++) wbase += wsum[i];
    int slot = wbase + sc - c;
#pragma unroll
    for (int i = 0; i < 32; i++) {
        int n = base + i;
        int p = -1;
        if (om[i]) {
            if (slot < CAP) {
                idx[(size_t)e * CAP + slot] = n;
                p = slot;
            }
            slot++;
        }
        pos[(size_t)n * 16 + e] = p;
    }
    if (tid == 255) cnt[e] = slot;
}

// ---------------- pair-bucket scan for output projection ----------------
// single block; buckets keyed by (e0,e1) = first two active experts
__global__ __launch_bounds__(256) void scan_pair(
    const int* __restrict__ onmaskv,
    int* __restrict__ ptok, int4* __restrict__ tiledesc, int* __restrict__ ntile_dev,
    int* __restrict__ ocnt, int* __restrict__ olist) {
    __shared__ int hist[256], cursor[256];
    __shared__ int wsum[4], wsum2[4];
    const int tid = threadIdx.x;
    if (tid == 0) *ocnt = 0;
    hist[tid] = 0;
    __syncthreads();
    // pass 1: histogram + overflow (experts beyond first two)
    for (int i = 0; i < 32; i++) {
        int n = tid * 32 + i;
        int m = onmaskv[n];
        if (!m) m = 1;
        int e0 = __ffs(m) - 1;
        int m2 = m & (m - 1);
        int e1 = m2 ? (__ffs(m2) - 1) : e0;
        atomicAdd(&hist[e0 * 16 + e1], 1);
        int mrest = m2 & (m2 - 1);
        while (mrest) {
            int e = __ffs(mrest) - 1;
            int s = atomicAdd(ocnt, 1);
            olist[2 * s] = n;
            olist[2 * s + 1] = e;
            mrest &= (mrest - 1);
        }
    }
    __syncthreads();
    // prefix over token counts
    const int lane = tid & 63, w = tid >> 6;
    int v = hist[tid];
    int s = v;
#pragma unroll
    for (int off = 1; off < 64; off <<= 1) {
        int t = __shfl_up(s, off);
        if (lane >= off) s += t;
    }
    if (lane == 63) wsum[w] = s;
    __syncthreads();
    int add = 0;
    for (int i = 0; i < w; i++) add += wsum[i];
    int excl = s + add - v;
    cursor[tid] = excl;
    // prefix over tile counts
    int nt = (v + 127) >> 7;
    int s2 = nt;
#pragma unroll
    for (int off = 1; off < 64; off <<= 1) {
        int t = __shfl_up(s2, off);
        if (lane >= off) s2 += t;
    }
    if (lane == 63) wsum2[w] = s2;
    __syncthreads();
    int add2 = 0;
    for (int i = 0; i < w; i++) add2 += wsum2[i];
    int texcl = s2 + add2 - nt;
    for (int m = 0; m < nt; m++)
        tiledesc[texcl + m] = make_int4(tid, excl + m * 128, min(128, v - m * 128), 0);
    if (tid == 255) *ntile_dev = texcl + nt;
    __syncthreads();
    // pass 2: scatter token ids (order within bucket does not affect output values)
    for (int i = 0; i < 32; i++) {
        int n = tid * 32 + i;
        int m = onmaskv[n];
        if (!m) m = 1;
        int e0 = __ffs(m) - 1;
        int m2 = m & (m - 1);
        int e1 = m2 ? (__ffs(m2) - 1) : e0;
        int slot = atomicAdd(&cursor[e0 * 16 + e1], 1);
        ptok[slot] = n;
    }
}

// ---------------- transposes ----------------
__global__ __launch_bounds__(256) void transpose_f32_bf16(
    const float* __restrict__ src, unsigned short* __restrict__ dst,
    int R, int Ccol, long ss, long ds) {
    __shared__ float tile[32][33];
    src += (size_t)blockIdx.z * ss;
    dst += (size_t)blockIdx.z * ds;
    int bx = blockIdx.x * 32, by = blockIdx.y * 32;
    int tx = threadIdx.x & 31, ty = threadIdx.x >> 5;
#pragma unroll
    for (int i = 0; i < 4; i++)
        tile[ty + i * 8][tx] = src[(size_t)(by + ty + i * 8) * Ccol + bx + tx];
    __syncthreads();
#pragma unroll
    for (int i = 0; i < 4; i++)
        dst[(size_t)(bx + ty + i * 8) * R + by + tx] = f2bf(tile[tx][ty + i * 8]);
}

__global__ __launch_bounds__(256) void transpose_u16(
    const unsigned short* __restrict__ src, unsigned short* __restrict__ dst,
    int R, int Ccol, long ss, long ds) {
    __shared__ unsigned short tile[32][33];
    src += (size_t)blockIdx.z * ss;
    dst += (size_t)blockIdx.z * ds;
    int bx = blockIdx.x * 32, by = blockIdx.y * 32;
    int tx = threadIdx.x & 31, ty = threadIdx.x >> 5;
#pragma unroll
    for (int i = 0; i < 4; i++)
        tile[ty + i * 8][tx] = src[(size_t)(by + ty + i * 8) * Ccol + bx + tx];
    __syncthreads();
#pragma unroll
    for (int i = 0; i < 4; i++)
        dst[(size_t)(bx + ty + i * 8) * R + by + tx] = tile[tx][ty + i * 8];
}

// ---------------- NT GEMM: Out[M,N] = A[M,K] * BT[N,K]^T (bf16 in, f32 out) ----------------
template <int CAUSAL>
__global__ __launch_bounds__(256) void gemm_nt(
    const unsigned short* __restrict__ A, long strideA, int lda,
    const unsigned short* __restrict__ BT, long strideB, int ldb,
    float* __restrict__ Out, long strideO, int ldo,
    int K, float scale) {
    __shared__ alignas(16) unsigned short As[128 * 64];
    __shared__ alignas(16) unsigned short Bs[128 * 64];
    const int bm = blockIdx.x * 128;
    const int bn = blockIdx.y * 128;
    if (CAUSAL && bn > bm + 127) return;
    A += (size_t)blockIdx.z * strideA;
    BT += (size_t)blockIdx.z * strideB;
    Out += (size_t)blockIdx.z * strideO;
    const int tid = threadIdx.x;
    const int wave = tid >> 6, lane = tid & 63;
    const int lr = lane & 15, lg = lane >> 4;
    const int wr = (wave >> 1) * 64, wc = (wave & 1) * 64;
    f32x4 acc[4][4] = {};

    for (int k0 = 0; k0 < K; k0 += 64) {
        __syncthreads();
#pragma unroll
        for (int i = 0; i < 4; i++) {
            int t = i * 256 + tid;
            int row = t >> 3;
            int kc = (t & 7) << 3;
            __builtin_amdgcn_global_load_lds(
                (const __attribute__((address_space(1))) void*)(A + (size_t)(bm + row) * lda + k0 + kc),
                (__attribute__((address_space(3))) void*)(As + (i * 4 + wave) * 512),
                16, 0, 0);
        }
#pragma unroll
        for (int i = 0; i < 4; i++) {
            int t = i * 256 + tid;
            int row = t >> 3;
            int kc = (t & 7) << 3;
            __builtin_amdgcn_global_load_lds(
                (const __attribute__((address_space(1))) void*)(BT + (size_t)(bn + row) * ldb + k0 + kc),
                (__attribute__((address_space(3))) void*)(Bs + (i * 4 + wave) * 512),
                16, 0, 0);
        }
        __syncthreads();
#pragma unroll
        for (int kk = 0; kk < 2; kk++) {
            bf16x8 a[4], b[4];
#pragma unroll
            for (int m = 0; m < 4; m++)
                a[m] = *(const bf16x8*)(As + (wr + m * 16 + lr) * 64 + kk * 32 + lg * 8);
#pragma unroll
            for (int n = 0; n < 4; n++)
                b[n] = *(const bf16x8*)(Bs + (wc + n * 16 + lr) * 64 + kk * 32 + lg * 8);
#pragma unroll
            for (int m = 0; m < 4; m++)
#pragma unroll
                for (int n = 0; n < 4; n++)
                    acc[m][n] = __builtin_amdgcn_mfma_f32_16x16x32_bf16(a[m], b[n], acc[m][n], 0, 0, 0);
        }
    }
#pragma unroll
    for (int m = 0; m < 4; m++) {
#pragma unroll
        for (int n = 0; n < 4; n++) {
#pragma unroll
            for (int r = 0; r < 4; r++) {
                int grow = bm + wr + m * 16 + lg * 4 + r;
                int gcol = bn + wc + n * 16 + lr;
                if (!CAUSAL || gcol <= grow)
                    Out[(size_t)grow * ldo + gcol] = acc[m][n][r] * scale;
            }
        }
    }
}

// ---------------- PV GEMM: split-K over causal-active chunks, atomic f32 accumulate ----------------
__global__ __launch_bounds__(256) void gemm_pv(
    const unsigned short* __restrict__ P, const unsigned short* __restrict__ vT,
    float* __restrict__ ob) {
    const int bm = blockIdx.x * 128;
    const int kb = blockIdx.y * 512;
    if (kb > bm + 127) return;
    const unsigned short* Pb = P + (size_t)blockIdx.z * Tt * 4096;
    const unsigned short* Vb = vT + (size_t)blockIdx.z * Dd * Tt;
    float* Ob = ob + (size_t)blockIdx.z * Tt * Dd;
    __shared__ alignas(16) unsigned short As[128 * 64];
    __shared__ alignas(16) unsigned short Bs[128 * 64];
    const int tid = threadIdx.x;
    const int wave = tid >> 6, lane = tid & 63;
    const int lr = lane & 15, lg = lane >> 4;
    const int wr = (wave >> 1) * 64, wc = (wave & 1) * 64;
    f32x4 acc[4][4] = {};

    for (int k0 = kb; k0 < kb + 512; k0 += 64) {
        __syncthreads();
#pragma unroll
        for (int i = 0; i < 4; i++) {
            int t = i * 256 + tid;
            int row = t >> 3;
            int kc = (t & 7) << 3;
            __builtin_amdgcn_global_load_lds(
                (const __attribute__((address_space(1))) void*)(Pb + (size_t)(bm + row) * 4096 + k0 + kc),
                (__attribute__((address_space(3))) void*)(As + (i * 4 + wave) * 512),
                16, 0, 0);
        }
#pragma unroll
        for (int i = 0; i < 4; i++) {
            int t = i * 256 + tid;
            int row = t >> 3;
            int kc = (t & 7) << 3;
            __builtin_amdgcn_global_load_lds(
                (const __attribute__((address_space(1))) void*)(Vb + (size_t)row * Tt + k0 + kc),
                (__attribute__((address_space(3))) void*)(Bs + (i * 4 + wave) * 512),
                16, 0, 0);
        }
        __syncthreads();
#pragma unroll
        for (int kk = 0; kk < 2; kk++) {
            bf16x8 a[4], b[4];
#pragma unroll
            for (int m = 0; m < 4; m++)
                a[m] = *(const bf16x8*)(As + (wr + m * 16 + lr) * 64 + kk * 32 + lg * 8);
#pragma unroll
            for (int n = 0; n < 4; n++)
                b[n] = *(const bf16x8*)(Bs + (wc + n * 16 + lr) * 64 + kk * 32 + lg * 8);
#pragma unroll
            for (int m = 0; m < 4; m++)
#pragma unroll
                for (int n = 0; n < 4; n++)
                    acc[m][n] = __builtin_amdgcn_mfma_f32_16x16x32_bf16(a[m], b[n], acc[m][n], 0, 0, 0);
        }
    }
#pragma unroll
    for (int m = 0; m < 4; m++)
#pragma unroll
        for (int n = 0; n < 4; n++)
#pragma unroll
            for (int r = 0; r < 4; r++) {
                int grow = bm + wr + m * 16 + lg * 4 + r;
                int gcol = wc + n * 16 + lr;
                atomicAdd(&Ob[(size_t)grow * Dd + gcol], acc[m][n][r]);
            }
}

// ---------------- gathered QKV projection, split-K=2 into bf16 partial halves ----------------
__global__ __launch_bounds__(256) void gemm_qkv_gather(
    const unsigned short* __restrict__ X, const unsigned short* __restrict__ W,
    const int* __restrict__ idx, const int* __restrict__ cnt,
    unsigned short* __restrict__ P) {
    const int z = blockIdx.z;  // e*2 + kchunk
    const int e = z >> 1, kc2 = z & 1;
    const int cn = min(cnt[e], CAP);
    const int bm = blockIdx.x * 128;
    if (bm >= cn) return;
    const int bn = blockIdx.y * 128;
    unsigned short* Ph = P + (size_t)kc2 * PHALF;
    __shared__ alignas(16) unsigned short As[128 * 64];
    __shared__ alignas(16) unsigned short Bs[128 * 64];
    __shared__ int toks[128];
    const int tid = threadIdx.x;
    if (tid < 128) toks[tid] = idx[(size_t)e * CAP + min(bm + tid, cn - 1)];
    const unsigned short* Wb = W + ((size_t)e * 384 + bn) * Cch;
    const int wave = tid >> 6, lane = tid & 63;
    const int lr = lane & 15, lg = lane >> 4;
    const int wr = (wave >> 1) * 64, wc = (wave & 1) * 64;
    f32x4 acc[4][4] = {};

    for (int k0 = kc2 * 1024; k0 < kc2 * 1024 + 1024; k0 += 64) {
        __syncthreads();
#pragma unroll
        for (int i = 0; i < 4; i++) {
            int t = i * 256 + tid;
            int row = t >> 3;
            int kc = (t & 7) << 3;
            __builtin_amdgcn_global_load_lds(
                (const __attribute__((address_space(1))) void*)(X + (size_t)toks[row] * Cch + k0 + kc),
                (__attribute__((address_space(3))) void*)(As + (i * 4 + wave) * 512),
                16, 0, 0);
        }
#pragma unroll
        for (int i = 0; i < 4; i++) {
            int t = i * 256 + tid;
            int row = t >> 3;
            int kc = (t & 7) << 3;
            __builtin_amdgcn_global_load_lds(
                (const __attribute__((address_space(1))) void*)(Wb + (size_t)row * Cch + k0 + kc),
                (__attribute__((address_space(3))) void*)(Bs + (i * 4 + wave) * 512),
                16, 0, 0);
        }
        __syncthreads();
#pragma unroll
        for (int kk = 0; kk < 2; kk++) {
            bf16x8 a[4], b[4];
#pragma unroll
            for (int m = 0; m < 4; m++)
                a[m] = *(const bf16x8*)(As + (wr + m * 16 + lr) * 64 + kk * 32 + lg * 8);
#pragma unroll
            for (int n = 0; n < 4; n++)
                b[n] = *(const bf16x8*)(Bs + (wc + n * 16 + lr) * 64 + kk * 32 + lg * 8);
#pragma unroll
            for (int m = 0; m < 4; m++)
#pragma unroll
                for (int n = 0; n < 4; n++)
                    acc[m][n] = __builtin_amdgcn_mfma_f32_16x16x32_bf16(a[m], b[n], acc[m][n], 0, 0, 0);
        }
    }
#pragma unroll
    for (int m = 0; m < 4; m++)
#pragma unroll
        for (int n = 0; n < 4; n++)
#pragma unroll
            for (int r = 0; r < 4; r++) {
                int slot = bm + wr + m * 16 + lg * 4 + r;
                int col = bn + wc + n * 16 + lr;
                if (slot < cn)
                    Ph[((size_t)e * CAP + slot) * 384 + col] = f2bf(acc[m][n][r]);
            }
}

// ---------------- combine q/k/v from two split-K halves ----------------
__global__ __launch_bounds__(256) void combine_qkv(
    const unsigned short* __restrict__ P, const float* __restrict__ rw,
    const int* __restrict__ pos,
    unsigned short* __restrict__ qb, unsigned short* __restrict__ kb,
    unsigned short* __restrict__ vb) {
    int i = blockIdx.x * 256 + threadIdx.x;
    int n = i >> 5;
    int d4 = (i & 31) << 2;
    float aq[4] = {}, ak[4] = {}, av[4] = {};
#pragma unroll
    for (int e = 0; e < 16; e++) {
        int p = pos[(size_t)n * 16 + e];
        if (p >= 0) {
            float w = rw[(size_t)n * 16 + e];
            const unsigned short* r0 = P + ((size_t)e * CAP + p) * 384 + d4;
            const unsigned short* r1 = r0 + PHALF;
            const u16x4 q0 = *(const u16x4*)(r0);
            const u16x4 k0 = *(const u16x4*)(r0 + 128);
            const u16x4 v0 = *(const u16x4*)(r0 + 256);
            const u16x4 q1 = *(const u16x4*)(r1);
            const u16x4 k1 = *(const u16x4*)(r1 + 128);
            const u16x4 v1 = *(const u16x4*)(r1 + 256);
#pragma unroll
            for (int j = 0; j < 4; j++) {
                aq[j] += w * (bf2f(q0[j]) + bf2f(q1[j]));
                ak[j] += w * (bf2f(k0[j]) + bf2f(k1[j]));
                av[j] += w * (bf2f(v0[j]) + bf2f(v1[j]));
            }
        }
    }
    u16x4 sq = {f2bf(aq[0]), f2bf(aq[1]), f2bf(aq[2]), f2bf(aq[3])};
    u16x4 sk = {f2bf(ak[0]), f2bf(ak[1]), f2bf(ak[2]), f2bf(ak[3])};
    u16x4 sv = {f2bf(av[0]), f2bf(av[1]), f2bf(av[2]), f2bf(av[3])};
    *(u16x4*)(qb + (size_t)n * Dd + d4) = sq;
    *(u16x4*)(kb + (size_t)n * Dd + d4) = sk;
    *(u16x4*)(vb + (size_t)n * Dd + d4) = sv;
}

// ---------------- causal row softmax, in-place f32 -> bf16 ----------------
__global__ __launch_bounds__(256) void softmax_kernel(float* __restrict__ scores) {
    int i = blockIdx.x, b = blockIdx.y;
    float* row = scores + ((size_t)b * Tt + i) * Tt;
    int nv = i + 1;
    float v[8];
    int cnt = 0;
    float mx = -1e30f;
    for (int j = threadIdx.x; j < nv; j += 256) {
        float t = row[j];
        v[cnt++] = t;
        mx = fmaxf(mx, t);
    }
    __shared__ float sred[4];
    int w = threadIdx.x >> 6;
#pragma unroll
    for (int off = 32; off; off >>= 1) mx = fmaxf(mx, __shfl_down(mx, off));
    if ((threadIdx.x & 63) == 0) sred[w] = mx;
    __syncthreads();
    float m = fmaxf(fmaxf(sred[0], sred[1]), fmaxf(sred[2], sred[3]));
    float s = 0.f;
    for (int t = 0; t < cnt; t++) {
        v[t] = __expf(v[t] - m);
        s += v[t];
    }
    __syncthreads();
#pragma unroll
    for (int off = 32; off; off >>= 1) s += __shfl_down(s, off);
    if ((threadIdx.x & 63) == 0) sred[w] = s;
    __syncthreads();
    float inv = 1.f / (sred[0] + sred[1] + sred[2] + sred[3]);
    unsigned short* prow = (unsigned short*)row;
    cnt = 0;
    for (int j = threadIdx.x; j < Tt; j += 256) {
        float pv = 0.f;
        if (j < nv) pv = v[cnt++] * inv;
        prow[j] = f2bf(pv);
    }
}

// ---------------- og2[n][256] = [rw_e0 * o | rw_e1 * o] (bf16) ----------------
__global__ __launch_bounds__(256) void og2_kernel(
    const float* __restrict__ ob, const float* __restrict__ rw,
    const int* __restrict__ onmaskv, unsigned short* __restrict__ og2) {
    int idx = blockIdx.x * 256 + threadIdx.x;  // (n, k4-group of 4)
    int n = idx >> 6;
    int k4 = (idx & 63) << 2;
    int m = onmaskv[n];
    if (!m) m = 1;
    int e0 = __ffs(m) - 1;
    int m2 = m & (m - 1);
    bool has2 = m2 != 0;
    int e1 = has2 ? (__ffs(m2) - 1) : e0;
    float wgt;
    int kb;
    if (k4 < 128) { wgt = rw[(size_t)n * 16 + e0]; kb = k4; }
    else { wgt = has2 ? rw[(size_t)n * 16 + e1] : 0.f; kb = k4 - 128; }
    const f32x4 o4 = *(const f32x4*)(ob + (size_t)n * Dd + kb);
    u16x4 st = {f2bf(wgt * o4[0]), f2bf(wgt * o4[1]), f2bf(wgt * o4[2]), f2bf(wgt * o4[3])};
    *(u16x4*)(og2 + (size_t)n * 256 + k4) = st;
}

// ---------------- pair-bucket output GEMM: out row written exactly once ----------------
// tile: 128 tokens (one bucket segment chunk) x 128 cols; K=256 = [op_i | op_j]
__global__ __launch_bounds__(256) void gemm_pair(
    const unsigned short* __restrict__ og2,   // [Nn][256] bf16
    const unsigned short* __restrict__ woT,   // [2048 c][E*128] bf16
    const int* __restrict__ ptok, const int4* __restrict__ tiledesc,
    const int* __restrict__ ntile_dev,
    float* __restrict__ out) {
    if (blockIdx.x >= *ntile_dev) return;
    const int4 td = tiledesc[blockIdx.x];
    const int ei = td.x >> 4, ej = td.x & 15;
    const int mstart = td.y, mcnt = td.z;
    const int bn = blockIdx.y * 128;
    __shared__ alignas(16) unsigned short As[128 * 64];
    __shared__ alignas(16) unsigned short Bs[128 * 64];
    __shared__ int toks[128];
    const int tid = threadIdx.x;
    if (tid < 128) toks[tid] = ptok[mstart + min(tid, mcnt - 1)];
    const int wave = tid >> 6, lane = tid & 63;
    const int lr = lane & 15, lg = lane >> 4;
    const int wr = (wave >> 1) * 64, wc = (wave & 1) * 64;
    f32x4 acc[4][4] = {};

#pragma unroll
    for (int ck = 0; ck < 4; ck++) {
        const int ebase = (ck < 2 ? ei : ej) * 128 + (ck & 1) * 64;
        const int abase = ck * 64;
        __syncthreads();  // first iter: also guards toks
#pragma unroll
        for (int q = 0; q < 4; q++) {
            int t = q * 256 + tid;
            int row = t >> 3;
            int kc = (t & 7) << 3;
            __builtin_amdgcn_global_load_lds(
                (const __attribute__((address_space(1))) void*)(og2 + (size_t)toks[row] * 256 + abase + kc),
                (__attribute__((address_space(3))) void*)(As + (q * 4 + wave) * 512),
                16, 0, 0);
        }
#pragma unroll
        for (int q = 0; q < 4; q++) {
            int t = q * 256 + tid;
            int row = t >> 3;
            int kc = (t & 7) << 3;
            __builtin_amdgcn_global_load_lds(
                (const __attribute__((address_space(1))) void*)(woT + (size_t)(bn + row) * 2048 + ebase + kc),
                (__attribute__((address_space(3))) void*)(Bs + (q * 4 + wave) * 512),
                16, 0, 0);
        }
        __syncthreads();
#pragma unroll
        for (int kk = 0; kk < 2; kk++) {
            bf16x8 a[4], b[4];
#pragma unroll
            for (int m = 0; m < 4; m++)
                a[m] = *(const bf16x8*)(As + (wr + m * 16 + lr) * 64 + kk * 32 + lg * 8);
#pragma unroll
            for (int n = 0; n < 4; n++)
                b[n] = *(const bf16x8*)(Bs + (wc + n * 16 + lr) * 64 + kk * 32 + lg * 8);
#pragma unroll
            for (int m = 0; m < 4; m++)
#pragma unroll
                for (int n = 0; n < 4; n++)
                    acc[m][n] = __builtin_amdgcn_mfma_f32_16x16x32_bf16(a[m], b[n], acc[m][n], 0, 0, 0);
        }
    }
#pragma unroll
    for (int m = 0; m < 4; m++)
#pragma unroll
        for (int n = 0; n < 4; n++)
#pragma unroll
            for (int r = 0; r < 4; r++) {
                int rowt = wr + m * 16 + lg * 4 + r;
                if (rowt < mcnt) {
                    int tok = toks[rowt];
                    out[(size_t)tok * 2048 + bn + wc + n * 16 + lr] = acc[m][n][r];
                }
            }
}

// ---------------- rare overflow path: experts beyond the first two (empty here) ----------------
__global__ __launch_bounds__(256) void overflow_kernel(
    const int* __restrict__ ocnt, const int* __restrict__ olist,
    const float* __restrict__ ob, const unsigned short* __restrict__ woT,
    const float* __restrict__ rw, float* __restrict__ out) {
    const int ne = *ocnt;
    __shared__ float osh[128];
    for (int it = blockIdx.x; it < ne; it += gridDim.x) {
        int n = olist[2 * it], e = olist[2 * it + 1];
        float wgt = rw[(size_t)n * 16 + e];
        if (threadIdx.x < 128) osh[threadIdx.x] = ob[(size_t)n * Dd + threadIdx.x];
        __syncthreads();
#pragma unroll 1
        for (int cc = 0; cc < 8; cc++) {
            int c = threadIdx.x * 8 + cc;
            float a = 0.f;
            for (int k = 0; k < 128; k++)
                a += osh[k] * bf2f(woT[(size_t)c * 2048 + e * 128 + k]);
            atomicAdd(&out[(size_t)n * 2048 + c], wgt * a);
        }
        __syncthreads();
    }
}

extern "C" void kernel_launch(void* const* d_in, const int* in_sizes, int n_in,
                              void* d_out, int out_size, void* d_ws, size_t ws_size,
                              hipStream_t stream) {
    (void)in_sizes; (void)n_in; (void)out_size; (void)ws_size;
    const float* hidden = (const float*)d_in[0];
    const float* sim = (const float*)d_in[1];
    const float* gates = (const float*)d_in[2];
    const float* qp = (const float*)d_in[3];
    const float* kp = (const float*)d_in[4];
    const float* vp = (const float*)d_in[5];
    const float* op = (const float*)d_in[6];
    const int* minex = (const int*)d_in[7];
    float* out = (float*)d_out;

    char* w = (char*)d_ws;
    size_t off = 0;
    auto alloc = [&](size_t bytes) -> char* {
        char* p = w + off;
        off = (off + bytes + 255) & ~(size_t)255;
        return p;
    };
    unsigned short* xb = (unsigned short*)alloc((size_t)Nn * Cch * 2);
    unsigned short* wqkvT = (unsigned short*)alloc((size_t)Ee * 384 * Cch * 2);
    unsigned short* woT = (unsigned short*)alloc((size_t)Cch * Ee * Dd * 2);
    float* rw = (float*)alloc((size_t)Nn * Ee * 4);
    float* sninv = (float*)alloc(256);
    float* simT = (float*)alloc((size_t)Ee * Cch * 4);
    int* cnt = (int*)alloc(256);
    int* onmaskv = (int*)alloc((size_t)Nn * 4);
    int* idx = (int*)alloc((size_t)Ee * CAP * 4);
    int* pos = (int*)alloc((size_t)Nn * 16 * 4);
    int* ptok = (int*)alloc((size_t)Nn * 4);
    int4* tiledesc = (int4*)alloc((size_t)MAXTILES * 16);
    int* ntile_dev = (int*)alloc(256);
    int* ocnt = (int*)alloc(256);
    int* olist = (int*)alloc((size_t)Nn * 14 * 2 * 4);
    char* big = alloc((size_t)Bsz * Tt * Tt * 4);  // P halves (50MB) / scores (67MB)
    unsigned short* qb = (unsigned short*)alloc((size_t)Nn * Dd * 2);
    unsigned short* kb = (unsigned short*)alloc((size_t)Nn * Dd * 2);
    unsigned short* vb = (unsigned short*)alloc((size_t)Nn * Dd * 2);
    unsigned short* vT = (unsigned short*)alloc((size_t)Bsz * Dd * Tt * 2);
    float* ob = (float*)alloc((size_t)Nn * Dd * 4);
    unsigned short* og2 = (unsigned short*)alloc((size_t)Nn * 256 * 2);
    unsigned short* Pc = (unsigned short*)big;
    float* scores = (float*)big;

    const float scale = 0.08838834764831845f;  // 1/sqrt(128)

    colnorm_kernel<<<1, 256, 0, stream>>>(sim, sninv);
    simt_kernel<<<(Ee * Cch) / 256, 256, 0, stream>>>(sim, simT);
    gating2_kernel<<<Nn / 4, 256, 0, stream>>>(hidden, simT, gates, sninv, minex, rw, xb, onmaskv);
    scan_kernel<<<Ee, 256, 0, stream>>>(onmaskv, idx, pos, cnt);
    scan_pair<<<1, 256, 0, stream>>>(onmaskv, ptok, tiledesc, ntile_dev, ocnt, olist);
    hipMemsetAsync(ob, 0, (size_t)Nn * Dd * 4, stream);

    // weight transposes (f32 -> bf16) into fused [E][384][C]
    transpose_f32_bf16<<<dim3(Dd / 32, Cch / 32, Ee), 256, 0, stream>>>(
        qp, wqkvT + 0 * Dd * Cch, Cch, Dd, (long)Cch * Dd, (long)384 * Cch);
    transpose_f32_bf16<<<dim3(Dd / 32, Cch / 32, Ee), 256, 0, stream>>>(
        kp, wqkvT + 1 * Dd * Cch, Cch, Dd, (long)Cch * Dd, (long)384 * Cch);
    transpose_f32_bf16<<<dim3(Dd / 32, Cch / 32, Ee), 256, 0, stream>>>(
        vp, wqkvT + 2 * Dd * Cch, Cch, Dd, (long)Cch * Dd, (long)384 * Cch);
    transpose_f32_bf16<<<dim3((Ee * Dd) / 32, Cch / 32, 1), 256, 0, stream>>>(
        op, woT, Ee * Dd, Cch, 0L, 0L);

    // gathered per-expert QKV projection (split-K=2), then combine
    gemm_qkv_gather<<<dim3(CAP / 128, 3, Ee * 2), 256, 0, stream>>>(xb, wqkvT, idx, cnt, Pc);
    combine_qkv<<<(Nn * 32) / 256, 256, 0, stream>>>(Pc, rw, pos, qb, kb, vb);

    // V transpose per batch
    transpose_u16<<<dim3(Dd / 32, Tt / 32, Bsz), 256, 0, stream>>>(
        vb, vT, Tt, Dd, (long)Tt * Dd, (long)Dd * Tt);

    // scores = Q K^T * scale (causal)
    gemm_nt<1><<<dim3(Tt / 128, Tt / 128, Bsz), 256, 0, stream>>>(
        qb, (long)Tt * Dd, Dd, kb, (long)Tt * Dd, Dd, scores, (long)Tt * Tt, Tt, Dd, scale);
    softmax_kernel<<<dim3(Tt, Bsz), 256, 0, stream>>>(scores);
    // O = P V  — split-K over causal-active 512-chunks, atomic accumulate
    gemm_pv<<<dim3(Tt / 128, Tt / 512, Bsz), 256, 0, stream>>>(
        (const unsigned short*)scores, vT, ob);

    // output projection: pair-bucket grouped GEMM, each out row stored exactly once
    og2_kernel<<<(Nn * 64) / 256, 256, 0, stream>>>(ob, rw, onmaskv, og2);
    gemm_pair<<<dim3(MAXTILES, Cch / 128), 256, 0, stream>>>(
        og2, woT, ptok, tiledesc, ntile_dev, out);
    overflow_kernel<<<256, 256, 0, stream>>>(ocnt, olist, ob, woT, rw, out);
}